// Round 9
// baseline (250.505 us; speedup 1.0000x reference)
//
#include <hip/hip_runtime.h>
#include <math.h>

#define VN 16
#define TN 2048
#define NROWS (VN*TN)   // 32768
#define DIN 64
#define HID 128
#define DKD 48
#define KNB 33
#define BR16 16
#define NRB (NROWS/BR16)   // 2048

// ---------------- Threefry-2x32, key = (0, 42) ----------------
__device__ __forceinline__ unsigned rotl32(unsigned x, int d){ return (x<<d)|(x>>(32-d)); }

__device__ __forceinline__ void tf2x32(unsigned c0, unsigned c1, unsigned& y0, unsigned& y1){
  const unsigned k0 = 0u, k1 = 42u;
  const unsigned k2 = k0 ^ k1 ^ 0x1BD11BDAu;
  unsigned x0 = c0, x1 = c1;
  x0 += k0; x1 += k1;
#define TF_R(r) { x0 += x1; x1 = rotl32(x1,(r)); x1 ^= x0; }
  TF_R(13) TF_R(15) TF_R(26) TF_R(6)   x0 += k1; x1 += k2 + 1u;
  TF_R(17) TF_R(29) TF_R(16) TF_R(24)  x0 += k2; x1 += k0 + 2u;
  TF_R(13) TF_R(15) TF_R(26) TF_R(6)   x0 += k0; x1 += k1 + 3u;
  TF_R(17) TF_R(29) TF_R(16) TF_R(24)  x0 += k1; x1 += k2 + 4u;
  TF_R(13) TF_R(15) TF_R(26) TF_R(6)   x0 += k2; x1 += k0 + 5u;
#undef TF_R
  y0 = x0; y1 = x1;
}

// exact f64 md for element n (partitionable 64-bit threefry stream, np-ref semantics)
__device__ __forceinline__ double md64_of(const float* __restrict__ max_depth, int n){
  unsigned y0, y1;
  tf2x32(0u, (unsigned)n, y0, y1);
  unsigned long long bits = (((unsigned long long)y0) << 32) | (unsigned long long)y1;
  unsigned long long fb = (bits >> 12) | 0x3FF0000000000000ull;   // [1,2)
  double f; __builtin_memcpy(&f, &fb, 8);
  f -= 1.0;
  return (double)max_depth[n] + f * (1.0/8192.0);
}

// ---------------- q/k/v MLPs: grid-split over {q,k,v}, 16 rows/block ----------------
// 256 threads. L1: u0=(tid&31)*4 units, r0=(tid>>5)*2 rows; per i: float2 LDS + float4 W -> 8 FMA.
// s_h transposed [row][unit] so L1 writes are lane-contiguous float4 (conflict-free) and
// L2 reads are broadcast float4.
__global__ __launch_bounds__(256) void qkv_kernel(const float* __restrict__ enc,
    const float* __restrict__ Wq1, const float* __restrict__ bq1,
    const float* __restrict__ Wq2, const float* __restrict__ bq2,
    const float* __restrict__ Wk1, const float* __restrict__ bk1,
    const float* __restrict__ Wk2, const float* __restrict__ bk2,
    const float* __restrict__ Wv1, const float* __restrict__ bv1,
    const float* __restrict__ Wv2, const float* __restrict__ bv2,
    float* __restrict__ qo, float* __restrict__ ko, float* __restrict__ vo)
{
  __shared__ float s_x[DIN][BR16+2];    // [64][18] i-major, 4.6 KB
  __shared__ float s_h[BR16][HID+4];    // [16][132] row-major, 8.45 KB
  int tid = threadIdx.x;
  int mm  = blockIdx.x / NRB;
  int base = (blockIdx.x - mm*NRB) * BR16;

  const float *W1, *b1, *W2, *b2; float* outp;
  if (mm == 0){ W1=Wq1; b1=bq1; W2=Wq2; b2=bq2; outp=qo; }
  else if (mm == 1){ W1=Wk1; b1=bk1; W2=Wk2; b2=bk2; outp=ko; }
  else        { W1=Wv1; b1=bv1; W2=Wv2; b2=bv2; outp=vo; }

  for (int idx = tid; idx < BR16*DIN; idx += 256){
    int r = idx >> 6, c = idx & 63;
    s_x[c][r] = enc[(size_t)(base+r)*DIN + c];
  }
  __syncthreads();

  // layer 1
  const int u0 = (tid & 31) * 4;
  const int r0 = (tid >> 5) * 2;
  float acc[2][4];
  {
    float c0=b1[u0], c1=b1[u0+1], c2=b1[u0+2], c3=b1[u0+3];
    acc[0][0]=c0; acc[0][1]=c1; acc[0][2]=c2; acc[0][3]=c3;
    acc[1][0]=c0; acc[1][1]=c1; acc[1][2]=c2; acc[1][3]=c3;
  }
  #pragma unroll 4
  for (int i=0;i<DIN;i++){
    const float2 xv = *reinterpret_cast<const float2*>(&s_x[i][r0]);
    const float4 wv = *reinterpret_cast<const float4*>(&W1[i*HID + u0]);
    acc[0][0]=fmaf(xv.x,wv.x,acc[0][0]); acc[0][1]=fmaf(xv.x,wv.y,acc[0][1]);
    acc[0][2]=fmaf(xv.x,wv.z,acc[0][2]); acc[0][3]=fmaf(xv.x,wv.w,acc[0][3]);
    acc[1][0]=fmaf(xv.y,wv.x,acc[1][0]); acc[1][1]=fmaf(xv.y,wv.y,acc[1][1]);
    acc[1][2]=fmaf(xv.y,wv.z,acc[1][2]); acc[1][3]=fmaf(xv.y,wv.w,acc[1][3]);
  }
  {
    float4 h0, h1;
    h0.x=fmaxf(acc[0][0],0.0f); h0.y=fmaxf(acc[0][1],0.0f);
    h0.z=fmaxf(acc[0][2],0.0f); h0.w=fmaxf(acc[0][3],0.0f);
    h1.x=fmaxf(acc[1][0],0.0f); h1.y=fmaxf(acc[1][1],0.0f);
    h1.z=fmaxf(acc[1][2],0.0f); h1.w=fmaxf(acc[1][3],0.0f);
    *reinterpret_cast<float4*>(&s_h[r0  ][u0]) = h0;
    *reinterpret_cast<float4*>(&s_h[r0+1][u0]) = h1;
  }
  __syncthreads();

  // layer 2: 16 rows x 48 outs; thread = (row rr, 3 outs uo0)
  const int uo0 = (tid & 15) * 3;
  const int rr  = tid >> 4;       // 0..15
  float a0=b2[uo0], a1=b2[uo0+1], a2=b2[uo0+2];
  #pragma unroll 4
  for (int i4=0;i4<HID/4;i4++){
    const float4 hv = *reinterpret_cast<const float4*>(&s_h[rr][i4*4]);
    const int ib = i4*4;
    a0=fmaf(hv.x, W2[(ib  )*DKD+uo0  ], a0);
    a1=fmaf(hv.x, W2[(ib  )*DKD+uo0+1], a1);
    a2=fmaf(hv.x, W2[(ib  )*DKD+uo0+2], a2);
    a0=fmaf(hv.y, W2[(ib+1)*DKD+uo0  ], a0);
    a1=fmaf(hv.y, W2[(ib+1)*DKD+uo0+1], a1);
    a2=fmaf(hv.y, W2[(ib+1)*DKD+uo0+2], a2);
    a0=fmaf(hv.z, W2[(ib+2)*DKD+uo0  ], a0);
    a1=fmaf(hv.z, W2[(ib+2)*DKD+uo0+1], a1);
    a2=fmaf(hv.z, W2[(ib+2)*DKD+uo0+2], a2);
    a0=fmaf(hv.w, W2[(ib+3)*DKD+uo0  ], a0);
    a1=fmaf(hv.w, W2[(ib+3)*DKD+uo0+1], a1);
    a2=fmaf(hv.w, W2[(ib+3)*DKD+uo0+2], a2);
  }
  {
    float* op = outp + (size_t)(base+rr)*DKD;
    op[uo0]=a0; op[uo0+1]=a1; op[uo0+2]=a2;
  }
}

// ---------------- attention: 4 rows/block (1 wave each), f32 scores/PV, f64 comp ----------------
__global__ void attn_kernel(const float* __restrict__ qv, const float* __restrict__ kv,
    const float* __restrict__ vv, const float* __restrict__ role_emb,
    const float* __restrict__ max_depth,
    const int* __restrict__ prev_values, const int* __restrict__ next_values,
    const int* __restrict__ window_indices, const int* __restrict__ indices,
    const float* __restrict__ prev_mask, const float* __restrict__ next_mask,
    const float* __restrict__ window_mask,
    float* __restrict__ ctx_out)
{
  __shared__ float s_q[4][DKD];
  __shared__ float s_p[4][KNB];
  __shared__ int   s_idx[4][KNB];
  int tid  = threadIdx.x;          // 256
  int wid  = tid >> 6;             // wave 0..3
  int lane = tid & 63;
  int n = blockIdx.x*4 + wid;
  int vrow = n >> 11;              // T = 2048
  int t    = n & 2047;

  if (lane < DKD) s_q[wid][lane] = qv[(size_t)n*DKD + lane];

  int v2l = lane & 15;
  double md_m = md64_of(max_depth, v2l*TN + t);
  double md_n = __shfl(md_m, 16 + vrow, 64);
  __syncthreads();

  float sc = -INFINITY;
  if (lane < KNB){
    int idx, role; bool valid;
    if (lane < 16){
      int m = lane*TN + t;
      idx   = prev_values[m];
      role  = (vrow<<4) + lane;
      valid = (prev_mask[m] == 0.0f);
    } else if (lane < 32){
      int v2 = lane - 16;
      int m = v2*TN + t;
      bool comp = md_n > md_m;       // exact f64 comparison (np-ref semantics)
      idx   = comp ? indices[m] : next_values[m];
      role  = 256 + (vrow<<4) + v2;
      valid = comp || (next_mask[m] == 0.0f);
    } else {
      idx   = window_indices[n];
      role  = 512 + vrow;
      valid = (window_mask[n] == 0.0f);
    }
    s_idx[wid][lane] = idx;
    const float4* kp = reinterpret_cast<const float4*>(kv + (size_t)idx*DKD);
    const float4* rp = reinterpret_cast<const float4*>(role_emb + (size_t)role*DKD);
    float acc = 0.0f;
    #pragma unroll
    for (int d4 = 0; d4 < DKD/4; d4++){
      float4 kk = kp[d4], rr = rp[d4];
      acc = fmaf(s_q[wid][4*d4+0], kk.x + rr.x, acc);
      acc = fmaf(s_q[wid][4*d4+1], kk.y + rr.y, acc);
      acc = fmaf(s_q[wid][4*d4+2], kk.z + rr.z, acc);
      acc = fmaf(s_q[wid][4*d4+3], kk.w + rr.w, acc);
    }
    sc = acc / 6.928203230275509f;   // sqrt(48)
    if (!valid) sc = -1e9f;
  }
  float mx = sc;
  #pragma unroll
  for (int o=32;o>0;o>>=1) mx = fmaxf(mx, __shfl_xor(mx, o, 64));
  double e = (lane < KNB) ? exp((double)sc - (double)mx) : 0.0;
  double ssum = e;
  #pragma unroll
  for (int o=32;o>0;o>>=1) ssum += __shfl_xor(ssum, o, 64);
  if (lane < KNB) s_p[wid][lane] = (float)(e / ssum);
  __syncthreads();

  if (lane < DKD){
    float c = 0.0f;
    for (int j=0;j<KNB;j++)
      c = fmaf(s_p[wid][j], vv[(size_t)s_idx[wid][j]*DKD + lane], c);
    ctx_out[(size_t)n*DKD + lane] = c;
  }
}

// ---------------- heads: 16 rows/block, hidden in registers, shuffle-reduced layer2 ----------------
__device__ __forceinline__ double nlogp_d(double x, double mu, double ls){
  double sp = fmax(ls, 0.0) + log1p(exp(-fabs(ls)));
  double s = sp + 1e-3;
  double z = (x - mu) / s;
  return 0.5*z*z + log(s) + 0.9189385332046727417803297; // 0.5*log(2*pi)
}

__global__ __launch_bounds__(256) void heads_kernel(const float* __restrict__ enc,
    const float* __restrict__ ctx, const float* __restrict__ uu,
    const float* __restrict__ Wd1, const float* __restrict__ bd1,
    const float* __restrict__ Wd2, const float* __restrict__ bd2,
    const float* __restrict__ Wm1, const float* __restrict__ bm1,
    const float* __restrict__ Wm2, const float* __restrict__ bm2,
    float* __restrict__ out)
{
  __shared__ float s_x[DIN+DKD][BR16+2];   // [112][18] 8.06 KB
  __shared__ float s_o[BR16][4];
  int tid = threadIdx.x;     // 256
  int base = blockIdx.x * BR16;

  for (int idx = tid; idx < BR16*DIN; idx += 256){
    int r = idx >> 6, c = idx & 63;
    s_x[c][r] = enc[(size_t)(base+r)*DIN + c];
  }
  for (int idx = tid; idx < BR16*DKD; idx += 256){
    int r = idx / DKD, c = idx - r*DKD;
    s_x[DIN + c][r] = ctx[(size_t)(base+r)*DKD + c];
  }
  __syncthreads();

  const int u0 = (tid & 31) * 4;
  const int r0 = (tid >> 5) * 2;

  float pd[2][2] = {{0.f,0.f},{0.f,0.f}};
  float pm[2][2] = {{0.f,0.f},{0.f,0.f}};

  // dp: hidden 112->128 into regs, partial dot vs Wd2
  {
    float acc[2][4];
    float c0=bd1[u0], c1=bd1[u0+1], c2=bd1[u0+2], c3=bd1[u0+3];
    acc[0][0]=c0; acc[0][1]=c1; acc[0][2]=c2; acc[0][3]=c3;
    acc[1][0]=c0; acc[1][1]=c1; acc[1][2]=c2; acc[1][3]=c3;
    #pragma unroll 4
    for (int i=0;i<DIN+DKD;i++){
      const float2 xv = *reinterpret_cast<const float2*>(&s_x[i][r0]);
      const float4 wv = *reinterpret_cast<const float4*>(&Wd1[i*HID + u0]);
      acc[0][0]=fmaf(xv.x,wv.x,acc[0][0]); acc[0][1]=fmaf(xv.x,wv.y,acc[0][1]);
      acc[0][2]=fmaf(xv.x,wv.z,acc[0][2]); acc[0][3]=fmaf(xv.x,wv.w,acc[0][3]);
      acc[1][0]=fmaf(xv.y,wv.x,acc[1][0]); acc[1][1]=fmaf(xv.y,wv.y,acc[1][1]);
      acc[1][2]=fmaf(xv.y,wv.z,acc[1][2]); acc[1][3]=fmaf(xv.y,wv.w,acc[1][3]);
    }
    #pragma unroll
    for (int j=0;j<4;j++){
      const float2 w2 = *reinterpret_cast<const float2*>(&Wd2[(u0+j)*2]);
      float h0 = fmaxf(acc[0][j],0.0f), h1 = fmaxf(acc[1][j],0.0f);
      pd[0][0]=fmaf(h0,w2.x,pd[0][0]); pd[0][1]=fmaf(h0,w2.y,pd[0][1]);
      pd[1][0]=fmaf(h1,w2.x,pd[1][0]); pd[1][1]=fmaf(h1,w2.y,pd[1][1]);
    }
  }
  // mp: hidden 64->128 into regs, partial dot vs Wm2
  {
    float acc[2][4];
    float c0=bm1[u0], c1=bm1[u0+1], c2=bm1[u0+2], c3=bm1[u0+3];
    acc[0][0]=c0; acc[0][1]=c1; acc[0][2]=c2; acc[0][3]=c3;
    acc[1][0]=c0; acc[1][1]=c1; acc[1][2]=c2; acc[1][3]=c3;
    #pragma unroll 4
    for (int i=0;i<DIN;i++){
      const float2 xv = *reinterpret_cast<const float2*>(&s_x[i][r0]);
      const float4 wv = *reinterpret_cast<const float4*>(&Wm1[i*HID + u0]);
      acc[0][0]=fmaf(xv.x,wv.x,acc[0][0]); acc[0][1]=fmaf(xv.x,wv.y,acc[0][1]);
      acc[0][2]=fmaf(xv.x,wv.z,acc[0][2]); acc[0][3]=fmaf(xv.x,wv.w,acc[0][3]);
      acc[1][0]=fmaf(xv.y,wv.x,acc[1][0]); acc[1][1]=fmaf(xv.y,wv.y,acc[1][1]);
      acc[1][2]=fmaf(xv.y,wv.z,acc[1][2]); acc[1][3]=fmaf(xv.y,wv.w,acc[1][3]);
    }
    #pragma unroll
    for (int j=0;j<4;j++){
      const float2 w2 = *reinterpret_cast<const float2*>(&Wm2[(u0+j)*2]);
      float h0 = fmaxf(acc[0][j],0.0f), h1 = fmaxf(acc[1][j],0.0f);
      pm[0][0]=fmaf(h0,w2.x,pm[0][0]); pm[0][1]=fmaf(h0,w2.y,pm[0][1]);
      pm[1][0]=fmaf(h1,w2.x,pm[1][0]); pm[1][1]=fmaf(h1,w2.y,pm[1][1]);
    }
  }
  // tree-reduce the 8 partials over the 32 lanes sharing (r0, r0+1)
  #pragma unroll
  for (int o=1;o<=16;o<<=1){
    pd[0][0]+=__shfl_xor(pd[0][0],o,64); pd[0][1]+=__shfl_xor(pd[0][1],o,64);
    pd[1][0]+=__shfl_xor(pd[1][0],o,64); pd[1][1]+=__shfl_xor(pd[1][1],o,64);
    pm[0][0]+=__shfl_xor(pm[0][0],o,64); pm[0][1]+=__shfl_xor(pm[0][1],o,64);
    pm[1][0]+=__shfl_xor(pm[1][0],o,64); pm[1][1]+=__shfl_xor(pm[1][1],o,64);
  }
  if ((tid & 31) == 0){
    #pragma unroll
    for (int rr=0;rr<2;rr++){
      s_o[r0+rr][0] = pd[rr][0] + bd2[0];
      s_o[r0+rr][1] = pd[rr][1] + bd2[1];
      s_o[r0+rr][2] = pm[rr][0] + bm2[0];
      s_o[r0+rr][3] = pm[rr][1] + bm2[1];
    }
  }
  __syncthreads();

  if (tid < BR16){
    double x = (double)uu[base + tid];
    out[base + tid] = (float)(nlogp_d(x, (double)s_o[tid][0], (double)s_o[tid][1]) +
                              nlogp_d(x, (double)s_o[tid][2], (double)s_o[tid][3]));
  }
}

extern "C" void kernel_launch(void* const* d_in, const int* in_sizes, int n_in,
                              void* d_out, int out_size, void* d_ws, size_t ws_size,
                              hipStream_t stream) {
  const float* encoded = (const float*)d_in[0];
  const float* u       = (const float*)d_in[1];
  const float* Wq1 = (const float*)d_in[2];  const float* bq1 = (const float*)d_in[3];
  const float* Wq2 = (const float*)d_in[4];  const float* bq2 = (const float*)d_in[5];
  const float* Wk1 = (const float*)d_in[6];  const float* bk1 = (const float*)d_in[7];
  const float* Wk2 = (const float*)d_in[8];  const float* bk2 = (const float*)d_in[9];
  const float* Wv1 = (const float*)d_in[10]; const float* bv1 = (const float*)d_in[11];
  const float* Wv2 = (const float*)d_in[12]; const float* bv2 = (const float*)d_in[13];
  const float* role_emb = (const float*)d_in[14];
  const float* Wd1 = (const float*)d_in[15]; const float* bd1 = (const float*)d_in[16];
  const float* Wd2 = (const float*)d_in[17]; const float* bd2 = (const float*)d_in[18];
  const float* Wm1 = (const float*)d_in[19]; const float* bm1 = (const float*)d_in[20];
  const float* Wm2 = (const float*)d_in[21]; const float* bm2 = (const float*)d_in[22];
  const int*   prev_values    = (const int*)d_in[23];
  const int*   next_values    = (const int*)d_in[24];
  const int*   window_indices = (const int*)d_in[25];
  const int*   indices        = (const int*)d_in[26];
  const float* prev_mask   = (const float*)d_in[27];
  const float* next_mask   = (const float*)d_in[28];
  const float* window_mask = (const float*)d_in[29];
  const float* max_depth   = (const float*)d_in[30];
  float* out = (float*)d_out;

  float* q  = (float*)d_ws;
  float* k  = q  + (size_t)NROWS*DKD;
  float* v  = k  + (size_t)NROWS*DKD;
  float* cx = v  + (size_t)NROWS*DKD;

  qkv_kernel<<<3*NRB, 256, 0, stream>>>(encoded,
      Wq1,bq1,Wq2,bq2, Wk1,bk1,Wk2,bk2, Wv1,bv1,Wv2,bv2, q, k, v);
  attn_kernel<<<NROWS/4, 256, 0, stream>>>(q, k, v, role_emb, max_depth,
      prev_values, next_values, window_indices, indices,
      prev_mask, next_mask, window_mask, cx);
  heads_kernel<<<NRB, 256, 0, stream>>>(encoded, cx, u,
      Wd1,bd1,Wd2,bd2, Wm1,bm1,Wm2,bm2, out);
}

// Round 10
// 208.244 us; speedup vs baseline: 1.2029x; 1.2029x over previous
//
#include <hip/hip_runtime.h>
#include <math.h>

#define VN 16
#define TN 2048
#define NROWS (VN*TN)   // 32768
#define DIN 64
#define HID 128
#define DKD 48
#define KNB 33
#define BR 32
#define KPAD 52
#define XPAD 36
#define HPAD 34

// ---------------- Threefry-2x32, key = (0, 42) ----------------
__device__ __forceinline__ unsigned rotl32(unsigned x, int d){ return (x<<d)|(x>>(32-d)); }

__device__ __forceinline__ void tf2x32(unsigned c0, unsigned c1, unsigned& y0, unsigned& y1){
  const unsigned k0 = 0u, k1 = 42u;
  const unsigned k2 = k0 ^ k1 ^ 0x1BD11BDAu;
  unsigned x0 = c0, x1 = c1;
  x0 += k0; x1 += k1;
#define TF_R(r) { x0 += x1; x1 = rotl32(x1,(r)); x1 ^= x0; }
  TF_R(13) TF_R(15) TF_R(26) TF_R(6)   x0 += k1; x1 += k2 + 1u;
  TF_R(17) TF_R(29) TF_R(16) TF_R(24)  x0 += k2; x1 += k0 + 2u;
  TF_R(13) TF_R(15) TF_R(26) TF_R(6)   x0 += k0; x1 += k1 + 3u;
  TF_R(17) TF_R(29) TF_R(16) TF_R(24)  x0 += k1; x1 += k2 + 4u;
  TF_R(13) TF_R(15) TF_R(26) TF_R(6)   x0 += k2; x1 += k0 + 5u;
#undef TF_R
  y0 = x0; y1 = x1;
}

// exact f64 md for element n (partitionable 64-bit threefry stream, np-ref semantics)
__device__ __forceinline__ double md64_of(const float* __restrict__ max_depth, int n){
  unsigned y0, y1;
  tf2x32(0u, (unsigned)n, y0, y1);
  unsigned long long bits = (((unsigned long long)y0) << 32) | (unsigned long long)y1;
  unsigned long long fb = (bits >> 12) | 0x3FF0000000000000ull;   // [1,2)
  double f; __builtin_memcpy(&f, &fb, 8);
  f -= 1.0;
  return (double)max_depth[n] + f * (1.0/8192.0);
}

// ---------------- prep: md64 + metadata transposes [V][T] -> [T][16] ----------------
__global__ __launch_bounds__(256) void prep_kernel(const float* __restrict__ max_depth,
    const int* __restrict__ pv, const int* __restrict__ nv, const int* __restrict__ ind,
    const float* __restrict__ pm, const float* __restrict__ nm,
    double* __restrict__ mdT, int* __restrict__ pvT, int* __restrict__ nvT,
    int* __restrict__ idxT, float* __restrict__ pmT, float* __restrict__ nmT)
{
  int n = blockIdx.x*256 + threadIdx.x;
  int v = n >> 11, t = n & 2047;
  int o = t*VN + v;
  mdT[o]  = md64_of(max_depth, n);
  pvT[o]  = pv[n];
  nvT[o]  = nv[n];
  idxT[o] = ind[n];
  pmT[o]  = pm[n];
  nmT[o]  = nm[n];
}

// ---------------- q/k/v MLPs: LDS-staged weights, 4x4 register tile ----------------
__global__ __launch_bounds__(256) void qkv_kernel(const float* __restrict__ enc,
    const float* __restrict__ Wq1, const float* __restrict__ bq1,
    const float* __restrict__ Wq2, const float* __restrict__ bq2,
    const float* __restrict__ Wk1, const float* __restrict__ bk1,
    const float* __restrict__ Wk2, const float* __restrict__ bk2,
    const float* __restrict__ Wv1, const float* __restrict__ bv1,
    const float* __restrict__ Wv2, const float* __restrict__ bv2,
    float* __restrict__ qo, float* __restrict__ ko, float* __restrict__ vo)
{
  __shared__ __align__(16) float s_x[DIN][XPAD];     // 9.2 KB
  __shared__ __align__(16) float s_h[HID][HPAD];     // 17.4 KB
  __shared__ __align__(16) float s_w[DIN*HID];       // 32 KB (union W1 / W2)
  int tid = threadIdx.x;
  int base = blockIdx.x * BR;

  for (int idx = tid; idx < BR*DIN; idx += 256){
    int r = idx >> 6, c = idx & 63;
    s_x[c][r] = enc[(size_t)(base+r)*DIN + c];
  }

  const float* W1s[3] = {Wq1, Wk1, Wv1};
  const float* b1s[3] = {bq1, bk1, bv1};
  const float* W2s[3] = {Wq2, Wk2, Wv2};
  const float* b2s[3] = {bq2, bk2, bv2};
  float* outs[3] = {qo, ko, vo};

  const int u0  = (tid & 31) * 4;   // layer1: 4 hidden units
  const int r0  = (tid >> 5) * 4;   // layer1: 4 rows
  const int uo0 = (tid & 15) * 3;   // layer2: 3 outputs
  const int rr0 = (tid >> 4) * 2;   // layer2: 2 rows

  for (int mm = 0; mm < 3; mm++){
    // stage W1 (64x128 = 2048 float4)
    {
      const float4* src = reinterpret_cast<const float4*>(W1s[mm]);
      float4* dst = reinterpret_cast<float4*>(s_w);
      for (int i = tid; i < DIN*HID/4; i += 256) dst[i] = src[i];
    }
    __syncthreads();

    // layer 1: 4 rows x 4 units per thread
    const float* __restrict__ b1 = b1s[mm];
    float acc[4][4];
    {
      float c0=b1[u0], c1=b1[u0+1], c2=b1[u0+2], c3=b1[u0+3];
      #pragma unroll
      for (int r=0;r<4;r++){ acc[r][0]=c0; acc[r][1]=c1; acc[r][2]=c2; acc[r][3]=c3; }
    }
    #pragma unroll 4
    for (int i=0;i<DIN;i++){
      const float4 xv = *reinterpret_cast<const float4*>(&s_x[i][r0]);
      const float4 wv = *reinterpret_cast<const float4*>(&s_w[i*HID + u0]);
      float xd[4] = {xv.x, xv.y, xv.z, xv.w};
      float wd[4] = {wv.x, wv.y, wv.z, wv.w};
      #pragma unroll
      for (int r=0;r<4;r++)
        #pragma unroll
        for (int j=0;j<4;j++)
          acc[r][j] = fmaf(xd[r], wd[j], acc[r][j]);
    }
    #pragma unroll
    for (int j=0;j<4;j++){
      float4 hv;
      hv.x=fmaxf(acc[0][j],0.0f); hv.y=fmaxf(acc[1][j],0.0f);
      hv.z=fmaxf(acc[2][j],0.0f); hv.w=fmaxf(acc[3][j],0.0f);
      *reinterpret_cast<float4*>(&s_h[u0+j][r0]) = hv;
    }
    __syncthreads();

    // stage W2 (128x48 = 1536 float4), overwrites W1
    {
      const float4* src = reinterpret_cast<const float4*>(W2s[mm]);
      float4* dst = reinterpret_cast<float4*>(s_w);
      for (int i = tid; i < HID*DKD/4; i += 256) dst[i] = src[i];
    }
    __syncthreads();

    // layer 2: 2 rows x 3 outputs per thread
    const float* __restrict__ b2p = b2s[mm];
    float a[2][3];
    {
      float c0=b2p[uo0], c1=b2p[uo0+1], c2=b2p[uo0+2];
      a[0][0]=c0; a[0][1]=c1; a[0][2]=c2;
      a[1][0]=c0; a[1][1]=c1; a[1][2]=c2;
    }
    #pragma unroll 4
    for (int i=0;i<HID;i++){
      const float2 hv = *reinterpret_cast<const float2*>(&s_h[i][rr0]);
      float w0 = s_w[i*DKD+uo0], w1 = s_w[i*DKD+uo0+1], w2 = s_w[i*DKD+uo0+2];
      a[0][0]=fmaf(hv.x,w0,a[0][0]); a[0][1]=fmaf(hv.x,w1,a[0][1]); a[0][2]=fmaf(hv.x,w2,a[0][2]);
      a[1][0]=fmaf(hv.y,w0,a[1][0]); a[1][1]=fmaf(hv.y,w1,a[1][1]); a[1][2]=fmaf(hv.y,w2,a[1][2]);
    }
    {
      float* op = outs[mm] + (size_t)(base+rr0)*DKD;
      op[uo0]=a[0][0]; op[uo0+1]=a[0][1]; op[uo0+2]=a[0][2];
      op[DKD+uo0]=a[1][0]; op[DKD+uo0+1]=a[1][1]; op[DKD+uo0+2]=a[1][2];
    }
    __syncthreads();
  }
}

// ---------------- attention: LDS-staged K + role, transposed metadata ----------------
__global__ __launch_bounds__(256) void attn_kernel(const float* __restrict__ qv,
    const float* __restrict__ kv, const float* __restrict__ vv,
    const float* __restrict__ role_emb, const double* __restrict__ mdT,
    const int* __restrict__ pvT, const int* __restrict__ nvT, const int* __restrict__ idxT,
    const float* __restrict__ pmT, const float* __restrict__ nmT,
    const int* __restrict__ window_indices, const float* __restrict__ window_mask,
    float* __restrict__ ctx_out)
{
  __shared__ __align__(16) float s_k[4][KNB][KPAD];   // 27.5 KB
  __shared__ __align__(16) float s_role[KNB][KPAD];   // 6.9 KB
  __shared__ __align__(16) float s_q[4][DKD];
  __shared__ float s_p[4][KNB];
  __shared__ int   s_idx[4][KNB];
  int tid  = threadIdx.x;          // 256
  int wid  = tid >> 6;
  int lane = tid & 63;
  int n = blockIdx.x*4 + wid;
  int vrow = n >> 11;              // all 4 rows in block share vrow (block 4-aligned, 2048|4)
  int t    = n & 2047;

  if (lane < DKD) s_q[wid][lane] = qv[(size_t)n*DKD + lane];

  // stage role rows (block-uniform: depend only on vrow)
  for (int idx = tid; idx < KNB*DKD; idx += 256){
    int j = idx / DKD, d = idx - j*DKD;
    int role = (j < 16) ? (vrow<<4)+j : ((j < 32) ? 256+(vrow<<4)+(j-16) : 512+vrow);
    s_role[j][d] = role_emb[(size_t)role*DKD + d];
  }

  int gidx = 0; bool valid = false;
  if (lane < KNB){
    if (lane < 16){
      int o = t*VN + lane;
      gidx  = pvT[o];
      valid = (pmT[o] == 0.0f);
    } else if (lane < 32){
      int v2 = lane - 16, o = t*VN + v2;
      bool comp = mdT[t*VN + vrow] > mdT[o];   // exact f64 (np-ref semantics)
      gidx  = comp ? idxT[o] : nvT[o];
      valid = comp || (nmT[o] == 0.0f);
    } else {
      gidx  = window_indices[n];
      valid = (window_mask[n] == 0.0f);
    }
    s_idx[wid][lane] = gidx;
  }

  // stage K rows cooperatively (wave-local): 33 coalesced 192B reads
  for (int j = 0; j < KNB; j++){
    int ij = __shfl(gidx, j, 64);
    if (lane < DKD) s_k[wid][j][lane] = kv[(size_t)ij*DKD + lane];
  }
  __syncthreads();

  float sc = -INFINITY;
  if (lane < KNB){
    float acc = 0.0f;
    #pragma unroll
    for (int d4 = 0; d4 < DKD/4; d4++){
      const float4 qq = *reinterpret_cast<const float4*>(&s_q[wid][4*d4]);
      const float4 kk = *reinterpret_cast<const float4*>(&s_k[wid][lane][4*d4]);
      const float4 rr = *reinterpret_cast<const float4*>(&s_role[lane][4*d4]);
      acc = fmaf(qq.x, kk.x + rr.x, acc);
      acc = fmaf(qq.y, kk.y + rr.y, acc);
      acc = fmaf(qq.z, kk.z + rr.z, acc);
      acc = fmaf(qq.w, kk.w + rr.w, acc);
    }
    sc = acc / 6.928203230275509f;   // sqrt(48)
    if (!valid) sc = -1e9f;
  }
  float mx = sc;
  #pragma unroll
  for (int o=32;o>0;o>>=1) mx = fmaxf(mx, __shfl_xor(mx, o, 64));
  float e = (lane < KNB) ? expf(sc - mx) : 0.0f;
  float ssum = e;
  #pragma unroll
  for (int o=32;o>0;o>>=1) ssum += __shfl_xor(ssum, o, 64);
  if (lane < KNB) s_p[wid][lane] = e / ssum;
  __syncthreads();

  if (lane < DKD){
    float c = 0.0f;
    for (int j=0;j<KNB;j++)
      c = fmaf(s_p[wid][j], vv[(size_t)s_idx[wid][j]*DKD + lane], c);
    ctx_out[(size_t)n*DKD + lane] = c;
  }
}

// ---------------- heads: LDS-staged Wd1/Wm1, hidden in regs, shuffle-reduced L2 ----------------
__device__ __forceinline__ double nlogp_d(double x, double mu, double ls){
  double sp = fmax(ls, 0.0) + log1p(exp(-fabs(ls)));
  double s = sp + 1e-3;
  double z = (x - mu) / s;
  return 0.5*z*z + log(s) + 0.9189385332046727417803297; // 0.5*log(2*pi)
}

__global__ __launch_bounds__(256) void heads_kernel(const float* __restrict__ enc,
    const float* __restrict__ ctx, const float* __restrict__ uu,
    const float* __restrict__ Wd1, const float* __restrict__ bd1,
    const float* __restrict__ Wd2, const float* __restrict__ bd2,
    const float* __restrict__ Wm1, const float* __restrict__ bm1,
    const float* __restrict__ Wm2, const float* __restrict__ bm2,
    float* __restrict__ out)
{
  __shared__ __align__(16) float s_x[DIN+DKD][XPAD];   // 16.1 KB
  __shared__ __align__(16) float s_w[(DIN+DKD)*HID];   // 56 KB (union Wd1 / Wm1)
  __shared__ float s_o[BR][4];
  int tid = threadIdx.x;     // 256
  int base = blockIdx.x * BR;

  for (int idx = tid; idx < BR*DIN; idx += 256){
    int r = idx >> 6, c = idx & 63;
    s_x[c][r] = enc[(size_t)(base+r)*DIN + c];
  }
  for (int idx = tid; idx < BR*DKD; idx += 256){
    int r = idx / DKD, c = idx - r*DKD;
    s_x[DIN + c][r] = ctx[(size_t)(base+r)*DKD + c];
  }
  // stage Wd1 (112x128 = 3584 float4)
  {
    const float4* src = reinterpret_cast<const float4*>(Wd1);
    float4* dst = reinterpret_cast<float4*>(s_w);
    for (int i = tid; i < (DIN+DKD)*HID/4; i += 256) dst[i] = src[i];
  }
  __syncthreads();

  const int u0 = (tid & 31) * 4;
  const int r0 = (tid >> 5) * 4;

  float pd[4][2] = {{0,0},{0,0},{0,0},{0,0}};
  float pm[4][2] = {{0,0},{0,0},{0,0},{0,0}};

  // dp: hidden 112->128 in regs, partial dot vs Wd2
  {
    float acc[4][4];
    float c0=bd1[u0], c1=bd1[u0+1], c2=bd1[u0+2], c3=bd1[u0+3];
    #pragma unroll
    for (int r=0;r<4;r++){ acc[r][0]=c0; acc[r][1]=c1; acc[r][2]=c2; acc[r][3]=c3; }
    #pragma unroll 4
    for (int i=0;i<DIN+DKD;i++){
      const float4 xv = *reinterpret_cast<const float4*>(&s_x[i][r0]);
      const float4 wv = *reinterpret_cast<const float4*>(&s_w[i*HID + u0]);
      float xd[4] = {xv.x, xv.y, xv.z, xv.w};
      float wd[4] = {wv.x, wv.y, wv.z, wv.w};
      #pragma unroll
      for (int r=0;r<4;r++)
        #pragma unroll
        for (int j=0;j<4;j++)
          acc[r][j] = fmaf(xd[r], wd[j], acc[r][j]);
    }
    #pragma unroll
    for (int j=0;j<4;j++){
      const float2 w2 = *reinterpret_cast<const float2*>(&Wd2[(u0+j)*2]);
      #pragma unroll
      for (int r=0;r<4;r++){
        float h = fmaxf(acc[r][j], 0.0f);
        pd[r][0] = fmaf(h, w2.x, pd[r][0]);
        pd[r][1] = fmaf(h, w2.y, pd[r][1]);
      }
    }
  }
  __syncthreads();   // dp done reading s_w
  // stage Wm1 (64x128 = 2048 float4)
  {
    const float4* src = reinterpret_cast<const float4*>(Wm1);
    float4* dst = reinterpret_cast<float4*>(s_w);
    for (int i = tid; i < DIN*HID/4; i += 256) dst[i] = src[i];
  }
  __syncthreads();

  // mp: hidden 64->128 in regs, partial dot vs Wm2
  {
    float acc[4][4];
    float c0=bm1[u0], c1=bm1[u0+1], c2=bm1[u0+2], c3=bm1[u0+3];
    #pragma unroll
    for (int r=0;r<4;r++){ acc[r][0]=c0; acc[r][1]=c1; acc[r][2]=c2; acc[r][3]=c3; }
    #pragma unroll 4
    for (int i=0;i<DIN;i++){
      const float4 xv = *reinterpret_cast<const float4*>(&s_x[i][r0]);
      const float4 wv = *reinterpret_cast<const float4*>(&s_w[i*HID + u0]);
      float xd[4] = {xv.x, xv.y, xv.z, xv.w};
      float wd[4] = {wv.x, wv.y, wv.z, wv.w};
      #pragma unroll
      for (int r=0;r<4;r++)
        #pragma unroll
        for (int j=0;j<4;j++)
          acc[r][j] = fmaf(xd[r], wd[j], acc[r][j]);
    }
    #pragma unroll
    for (int j=0;j<4;j++){
      const float2 w2 = *reinterpret_cast<const float2*>(&Wm2[(u0+j)*2]);
      #pragma unroll
      for (int r=0;r<4;r++){
        float h = fmaxf(acc[r][j], 0.0f);
        pm[r][0] = fmaf(h, w2.x, pm[r][0]);
        pm[r][1] = fmaf(h, w2.y, pm[r][1]);
      }
    }
  }
  // tree-reduce partials over the 32 lanes sharing rows r0..r0+3
  #pragma unroll
  for (int o=1;o<=16;o<<=1){
    #pragma unroll
    for (int r=0;r<4;r++){
      pd[r][0]+=__shfl_xor(pd[r][0],o,64); pd[r][1]+=__shfl_xor(pd[r][1],o,64);
      pm[r][0]+=__shfl_xor(pm[r][0],o,64); pm[r][1]+=__shfl_xor(pm[r][1],o,64);
    }
  }
  if ((tid & 31) == 0){
    #pragma unroll
    for (int r=0;r<4;r++){
      s_o[r0+r][0] = pd[r][0] + bd2[0];
      s_o[r0+r][1] = pd[r][1] + bd2[1];
      s_o[r0+r][2] = pm[r][0] + bm2[0];
      s_o[r0+r][3] = pm[r][1] + bm2[1];
    }
  }
  __syncthreads();

  if (tid < BR){
    double x = (double)uu[base + tid];
    out[base + tid] = (float)(nlogp_d(x, (double)s_o[tid][0], (double)s_o[tid][1]) +
                              nlogp_d(x, (double)s_o[tid][2], (double)s_o[tid][3]));
  }
}

extern "C" void kernel_launch(void* const* d_in, const int* in_sizes, int n_in,
                              void* d_out, int out_size, void* d_ws, size_t ws_size,
                              hipStream_t stream) {
  const float* encoded = (const float*)d_in[0];
  const float* u       = (const float*)d_in[1];
  const float* Wq1 = (const float*)d_in[2];  const float* bq1 = (const float*)d_in[3];
  const float* Wq2 = (const float*)d_in[4];  const float* bq2 = (const float*)d_in[5];
  const float* Wk1 = (const float*)d_in[6];  const float* bk1 = (const float*)d_in[7];
  const float* Wk2 = (const float*)d_in[8];  const float* bk2 = (const float*)d_in[9];
  const float* Wv1 = (const float*)d_in[10]; const float* bv1 = (const float*)d_in[11];
  const float* Wv2 = (const float*)d_in[12]; const float* bv2 = (const float*)d_in[13];
  const float* role_emb = (const float*)d_in[14];
  const float* Wd1 = (const float*)d_in[15]; const float* bd1 = (const float*)d_in[16];
  const float* Wd2 = (const float*)d_in[17]; const float* bd2 = (const float*)d_in[18];
  const float* Wm1 = (const float*)d_in[19]; const float* bm1 = (const float*)d_in[20];
  const float* Wm2 = (const float*)d_in[21]; const float* bm2 = (const float*)d_in[22];
  const int*   prev_values    = (const int*)d_in[23];
  const int*   next_values    = (const int*)d_in[24];
  const int*   window_indices = (const int*)d_in[25];
  const int*   indices        = (const int*)d_in[26];
  const float* prev_mask   = (const float*)d_in[27];
  const float* next_mask   = (const float*)d_in[28];
  const float* window_mask = (const float*)d_in[29];
  const float* max_depth   = (const float*)d_in[30];
  float* out = (float*)d_out;

  double* mdT = (double*)d_ws;                  // 32768 f64
  float* q  = (float*)(mdT + NROWS);
  float* k  = q  + (size_t)NROWS*DKD;
  float* v  = k  + (size_t)NROWS*DKD;
  float* cx = v  + (size_t)NROWS*DKD;
  int*   pvT  = (int*)(cx + (size_t)NROWS*DKD);
  int*   nvT  = pvT + NROWS;
  int*   idxT = nvT + NROWS;
  float* pmT  = (float*)(idxT + NROWS);
  float* nmT  = pmT + NROWS;

  prep_kernel<<<NROWS/256, 256, 0, stream>>>(max_depth,
      prev_values, next_values, indices, prev_mask, next_mask,
      mdT, pvT, nvT, idxT, pmT, nmT);
  qkv_kernel<<<NROWS/BR, 256, 0, stream>>>(encoded,
      Wq1,bq1,Wq2,bq2, Wk1,bk1,Wk2,bk2, Wv1,bv1,Wv2,bv2, q, k, v);
  attn_kernel<<<NROWS/4, 256, 0, stream>>>(q, k, v, role_emb, mdT,
      pvT, nvT, idxT, pmT, nmT, window_indices, window_mask, cx);
  heads_kernel<<<NROWS/BR, 256, 0, stream>>>(encoded, cx, u,
      Wd1,bd1,Wd2,bd2, Wm1,bm1,Wm2,bm2, out);
}

// Round 11
// 176.557 us; speedup vs baseline: 1.4188x; 1.1795x over previous
//
#include <hip/hip_runtime.h>
#include <math.h>

#define VN 16
#define TN 2048
#define NROWS (VN*TN)   // 32768
#define DIN 64
#define HID 128
#define DKD 48
#define KNB 33
#define BR 32
#define KPAD 52
#define XPAD 36
#define HPAD 34

// ---------------- Threefry-2x32, key = (0, 42) ----------------
__device__ __forceinline__ unsigned rotl32(unsigned x, int d){ return (x<<d)|(x>>(32-d)); }

__device__ __forceinline__ void tf2x32(unsigned c0, unsigned c1, unsigned& y0, unsigned& y1){
  const unsigned k0 = 0u, k1 = 42u;
  const unsigned k2 = k0 ^ k1 ^ 0x1BD11BDAu;
  unsigned x0 = c0, x1 = c1;
  x0 += k0; x1 += k1;
#define TF_R(r) { x0 += x1; x1 = rotl32(x1,(r)); x1 ^= x0; }
  TF_R(13) TF_R(15) TF_R(26) TF_R(6)   x0 += k1; x1 += k2 + 1u;
  TF_R(17) TF_R(29) TF_R(16) TF_R(24)  x0 += k2; x1 += k0 + 2u;
  TF_R(13) TF_R(15) TF_R(26) TF_R(6)   x0 += k0; x1 += k1 + 3u;
  TF_R(17) TF_R(29) TF_R(16) TF_R(24)  x0 += k1; x1 += k2 + 4u;
  TF_R(13) TF_R(15) TF_R(26) TF_R(6)   x0 += k2; x1 += k0 + 5u;
#undef TF_R
  y0 = x0; y1 = x1;
}

// exact f64 md for element n (partitionable 64-bit threefry stream, np-ref semantics)
__device__ __forceinline__ double md64_of(const float* __restrict__ max_depth, int n){
  unsigned y0, y1;
  tf2x32(0u, (unsigned)n, y0, y1);
  unsigned long long bits = (((unsigned long long)y0) << 32) | (unsigned long long)y1;
  unsigned long long fb = (bits >> 12) | 0x3FF0000000000000ull;   // [1,2)
  double f; __builtin_memcpy(&f, &fb, 8);
  f -= 1.0;
  return (double)max_depth[n] + f * (1.0/8192.0);
}

// ---------------- prep: md64 + metadata transposes [V][T] -> [T][16] ----------------
__global__ __launch_bounds__(256) void prep_kernel(const float* __restrict__ max_depth,
    const int* __restrict__ pv, const int* __restrict__ nv, const int* __restrict__ ind,
    const float* __restrict__ pm, const float* __restrict__ nm,
    double* __restrict__ mdT, int* __restrict__ pvT, int* __restrict__ nvT,
    int* __restrict__ idxT, float* __restrict__ pmT, float* __restrict__ nmT)
{
  int n = blockIdx.x*256 + threadIdx.x;
  int v = n >> 11, t = n & 2047;
  int o = t*VN + v;
  mdT[o]  = md64_of(max_depth, n);
  pvT[o]  = pv[n];
  nvT[o]  = nv[n];
  idxT[o] = ind[n];
  pmT[o]  = pm[n];
  nmT[o]  = nm[n];
}

// ---------------- q/k/v MLPs: LDS-staged weights, 4x4 register tile ----------------
__global__ __launch_bounds__(256) void qkv_kernel(const float* __restrict__ enc,
    const float* __restrict__ Wq1, const float* __restrict__ bq1,
    const float* __restrict__ Wq2, const float* __restrict__ bq2,
    const float* __restrict__ Wk1, const float* __restrict__ bk1,
    const float* __restrict__ Wk2, const float* __restrict__ bk2,
    const float* __restrict__ Wv1, const float* __restrict__ bv1,
    const float* __restrict__ Wv2, const float* __restrict__ bv2,
    float* __restrict__ qo, float* __restrict__ ko, float* __restrict__ vo)
{
  __shared__ __align__(16) float s_x[DIN][XPAD];     // 9.2 KB
  __shared__ __align__(16) float s_h[HID][HPAD];     // 17.4 KB
  __shared__ __align__(16) float s_w[DIN*HID];       // 32 KB (union W1 / W2)
  int tid = threadIdx.x;
  int base = blockIdx.x * BR;

  for (int idx = tid; idx < BR*DIN; idx += 256){
    int r = idx >> 6, c = idx & 63;
    s_x[c][r] = enc[(size_t)(base+r)*DIN + c];
  }

  const float* W1s[3] = {Wq1, Wk1, Wv1};
  const float* b1s[3] = {bq1, bk1, bv1};
  const float* W2s[3] = {Wq2, Wk2, Wv2};
  const float* b2s[3] = {bq2, bk2, bv2};
  float* outs[3] = {qo, ko, vo};

  const int u0  = (tid & 31) * 4;   // layer1: 4 hidden units
  const int r0  = (tid >> 5) * 4;   // layer1: 4 rows
  const int uo0 = (tid & 15) * 3;   // layer2: 3 outputs
  const int rr0 = (tid >> 4) * 2;   // layer2: 2 rows

  for (int mm = 0; mm < 3; mm++){
    // stage W1 (64x128 = 2048 float4)
    {
      const float4* src = reinterpret_cast<const float4*>(W1s[mm]);
      float4* dst = reinterpret_cast<float4*>(s_w);
      for (int i = tid; i < DIN*HID/4; i += 256) dst[i] = src[i];
    }
    __syncthreads();

    // layer 1: 4 rows x 4 units per thread
    const float* __restrict__ b1 = b1s[mm];
    float acc[4][4];
    {
      float c0=b1[u0], c1=b1[u0+1], c2=b1[u0+2], c3=b1[u0+3];
      #pragma unroll
      for (int r=0;r<4;r++){ acc[r][0]=c0; acc[r][1]=c1; acc[r][2]=c2; acc[r][3]=c3; }
    }
    #pragma unroll 4
    for (int i=0;i<DIN;i++){
      const float4 xv = *reinterpret_cast<const float4*>(&s_x[i][r0]);
      const float4 wv = *reinterpret_cast<const float4*>(&s_w[i*HID + u0]);
      float xd[4] = {xv.x, xv.y, xv.z, xv.w};
      float wd[4] = {wv.x, wv.y, wv.z, wv.w};
      #pragma unroll
      for (int r=0;r<4;r++)
        #pragma unroll
        for (int j=0;j<4;j++)
          acc[r][j] = fmaf(xd[r], wd[j], acc[r][j]);
    }
    #pragma unroll
    for (int j=0;j<4;j++){
      float4 hv;
      hv.x=fmaxf(acc[0][j],0.0f); hv.y=fmaxf(acc[1][j],0.0f);
      hv.z=fmaxf(acc[2][j],0.0f); hv.w=fmaxf(acc[3][j],0.0f);
      *reinterpret_cast<float4*>(&s_h[u0+j][r0]) = hv;
    }
    __syncthreads();

    // stage W2 (128x48 = 1536 float4), overwrites W1
    {
      const float4* src = reinterpret_cast<const float4*>(W2s[mm]);
      float4* dst = reinterpret_cast<float4*>(s_w);
      for (int i = tid; i < HID*DKD/4; i += 256) dst[i] = src[i];
    }
    __syncthreads();

    // layer 2: 2 rows x 3 outputs per thread
    const float* __restrict__ b2p = b2s[mm];
    float a[2][3];
    {
      float c0=b2p[uo0], c1=b2p[uo0+1], c2=b2p[uo0+2];
      a[0][0]=c0; a[0][1]=c1; a[0][2]=c2;
      a[1][0]=c0; a[1][1]=c1; a[1][2]=c2;
    }
    #pragma unroll 4
    for (int i=0;i<HID;i++){
      const float2 hv = *reinterpret_cast<const float2*>(&s_h[i][rr0]);
      float w0 = s_w[i*DKD+uo0], w1 = s_w[i*DKD+uo0+1], w2 = s_w[i*DKD+uo0+2];
      a[0][0]=fmaf(hv.x,w0,a[0][0]); a[0][1]=fmaf(hv.x,w1,a[0][1]); a[0][2]=fmaf(hv.x,w2,a[0][2]);
      a[1][0]=fmaf(hv.y,w0,a[1][0]); a[1][1]=fmaf(hv.y,w1,a[1][1]); a[1][2]=fmaf(hv.y,w2,a[1][2]);
    }
    {
      float* op = outs[mm] + (size_t)(base+rr0)*DKD;
      op[uo0]=a[0][0]; op[uo0+1]=a[0][1]; op[uo0+2]=a[0][2];
      op[DKD+uo0]=a[1][0]; op[DKD+uo0+1]=a[1][1]; op[DKD+uo0+2]=a[1][2];
    }
    __syncthreads();
  }
}

// ---------------- attention: direct K gather, LDS role, transposed metadata ----------------
__global__ __launch_bounds__(256) void attn_kernel(const float* __restrict__ qv,
    const float* __restrict__ kv, const float* __restrict__ vv,
    const float* __restrict__ role_emb, const double* __restrict__ mdT,
    const int* __restrict__ pvT, const int* __restrict__ nvT, const int* __restrict__ idxT,
    const float* __restrict__ pmT, const float* __restrict__ nmT,
    const int* __restrict__ window_indices, const float* __restrict__ window_mask,
    float* __restrict__ ctx_out)
{
  __shared__ __align__(16) float s_role[KNB][KPAD];   // 6.9 KB (block-uniform)
  __shared__ __align__(16) float s_q[4][DKD];
  __shared__ float s_p[4][KNB];
  __shared__ int   s_idx[4][KNB];
  int tid  = threadIdx.x;          // 256
  int wid  = tid >> 6;
  int lane = tid & 63;
  int n = blockIdx.x*4 + wid;
  int vrow = n >> 11;              // all 4 rows in block share vrow
  int t    = n & 2047;

  if (lane < DKD) s_q[wid][lane] = qv[(size_t)n*DKD + lane];

  // stage role rows (block-uniform: depend only on vrow)
  for (int idx = tid; idx < KNB*DKD; idx += 256){
    int j = idx / DKD, d = idx - j*DKD;
    int role = (j < 16) ? (vrow<<4)+j : ((j < 32) ? 256+(vrow<<4)+(j-16) : 512+vrow);
    s_role[j][d] = role_emb[(size_t)role*DKD + d];
  }
  __syncthreads();

  float sc = -INFINITY;
  if (lane < KNB){
    int gidx; bool valid;
    if (lane < 16){
      int o = t*VN + lane;
      gidx  = pvT[o];
      valid = (pmT[o] == 0.0f);
    } else if (lane < 32){
      int v2 = lane - 16, o = t*VN + v2;
      bool comp = mdT[t*VN + vrow] > mdT[o];   // exact f64 (np-ref semantics)
      gidx  = comp ? idxT[o] : nvT[o];
      valid = comp || (nmT[o] == 0.0f);
    } else {
      gidx  = window_indices[n];
      valid = (window_mask[n] == 0.0f);
    }
    s_idx[wid][lane] = gidx;
    // direct per-lane K gather: 3 independent float4 loads (HW-pipelined)
    const float4* kp = reinterpret_cast<const float4*>(kv + (size_t)gidx*DKD);
    float acc = 0.0f;
    #pragma unroll
    for (int d4 = 0; d4 < DKD/4; d4++){
      const float4 qq = *reinterpret_cast<const float4*>(&s_q[wid][4*d4]);
      const float4 rr = *reinterpret_cast<const float4*>(&s_role[lane][4*d4]);
      const float4 kk = kp[d4];
      acc = fmaf(qq.x, kk.x + rr.x, acc);
      acc = fmaf(qq.y, kk.y + rr.y, acc);
      acc = fmaf(qq.z, kk.z + rr.z, acc);
      acc = fmaf(qq.w, kk.w + rr.w, acc);
    }
    sc = acc / 6.928203230275509f;   // sqrt(48)
    if (!valid) sc = -1e9f;
  }
  float mx = sc;
  #pragma unroll
  for (int o=32;o>0;o>>=1) mx = fmaxf(mx, __shfl_xor(mx, o, 64));
  float e = (lane < KNB) ? expf(sc - mx) : 0.0f;
  float ssum = e;
  #pragma unroll
  for (int o=32;o>0;o>>=1) ssum += __shfl_xor(ssum, o, 64);
  if (lane < KNB) s_p[wid][lane] = e / ssum;

  if (lane < DKD){
    float c = 0.0f;
    #pragma unroll 8
    for (int j=0;j<KNB;j++)
      c = fmaf(s_p[wid][j], vv[(size_t)s_idx[wid][j]*DKD + lane], c);
    ctx_out[(size_t)n*DKD + lane] = c;
  }
}

// ---------------- heads: LDS-staged Wd1/Wm1, hidden in regs, shuffle-reduced L2 ----------------
__device__ __forceinline__ double nlogp_d(double x, double mu, double ls){
  double sp = fmax(ls, 0.0) + log1p(exp(-fabs(ls)));
  double s = sp + 1e-3;
  double z = (x - mu) / s;
  return 0.5*z*z + log(s) + 0.9189385332046727417803297; // 0.5*log(2*pi)
}

__global__ __launch_bounds__(256) void heads_kernel(const float* __restrict__ enc,
    const float* __restrict__ ctx, const float* __restrict__ uu,
    const float* __restrict__ Wd1, const float* __restrict__ bd1,
    const float* __restrict__ Wd2, const float* __restrict__ bd2,
    const float* __restrict__ Wm1, const float* __restrict__ bm1,
    const float* __restrict__ Wm2, const float* __restrict__ bm2,
    float* __restrict__ out)
{
  __shared__ __align__(16) float s_x[DIN+DKD][XPAD];   // 16.1 KB
  __shared__ __align__(16) float s_w[(DIN+DKD)*HID];   // 56 KB (union Wd1 / Wm1)
  __shared__ float s_o[BR][4];
  int tid = threadIdx.x;     // 256
  int base = blockIdx.x * BR;

  for (int idx = tid; idx < BR*DIN; idx += 256){
    int r = idx >> 6, c = idx & 63;
    s_x[c][r] = enc[(size_t)(base+r)*DIN + c];
  }
  for (int idx = tid; idx < BR*DKD; idx += 256){
    int r = idx / DKD, c = idx - r*DKD;
    s_x[DIN + c][r] = ctx[(size_t)(base+r)*DKD + c];
  }
  // stage Wd1 (112x128 = 3584 float4)
  {
    const float4* src = reinterpret_cast<const float4*>(Wd1);
    float4* dst = reinterpret_cast<float4*>(s_w);
    for (int i = tid; i < (DIN+DKD)*HID/4; i += 256) dst[i] = src[i];
  }
  __syncthreads();

  const int u0 = (tid & 31) * 4;
  const int r0 = (tid >> 5) * 4;

  float pd[4][2] = {{0,0},{0,0},{0,0},{0,0}};
  float pm[4][2] = {{0,0},{0,0},{0,0},{0,0}};

  // dp: hidden 112->128 in regs, partial dot vs Wd2
  {
    float acc[4][4];
    float c0=bd1[u0], c1=bd1[u0+1], c2=bd1[u0+2], c3=bd1[u0+3];
    #pragma unroll
    for (int r=0;r<4;r++){ acc[r][0]=c0; acc[r][1]=c1; acc[r][2]=c2; acc[r][3]=c3; }
    #pragma unroll 4
    for (int i=0;i<DIN+DKD;i++){
      const float4 xv = *reinterpret_cast<const float4*>(&s_x[i][r0]);
      const float4 wv = *reinterpret_cast<const float4*>(&s_w[i*HID + u0]);
      float xd[4] = {xv.x, xv.y, xv.z, xv.w};
      float wd[4] = {wv.x, wv.y, wv.z, wv.w};
      #pragma unroll
      for (int r=0;r<4;r++)
        #pragma unroll
        for (int j=0;j<4;j++)
          acc[r][j] = fmaf(xd[r], wd[j], acc[r][j]);
    }
    #pragma unroll
    for (int j=0;j<4;j++){
      const float2 w2 = *reinterpret_cast<const float2*>(&Wd2[(u0+j)*2]);
      #pragma unroll
      for (int r=0;r<4;r++){
        float h = fmaxf(acc[r][j], 0.0f);
        pd[r][0] = fmaf(h, w2.x, pd[r][0]);
        pd[r][1] = fmaf(h, w2.y, pd[r][1]);
      }
    }
  }
  __syncthreads();   // dp done reading s_w
  // stage Wm1 (64x128 = 2048 float4)
  {
    const float4* src = reinterpret_cast<const float4*>(Wm1);
    float4* dst = reinterpret_cast<float4*>(s_w);
    for (int i = tid; i < DIN*HID/4; i += 256) dst[i] = src[i];
  }
  __syncthreads();

  // mp: hidden 64->128 in regs, partial dot vs Wm2
  {
    float acc[4][4];
    float c0=bm1[u0], c1=bm1[u0+1], c2=bm1[u0+2], c3=bm1[u0+3];
    #pragma unroll
    for (int r=0;r<4;r++){ acc[r][0]=c0; acc[r][1]=c1; acc[r][2]=c2; acc[r][3]=c3; }
    #pragma unroll 4
    for (int i=0;i<DIN;i++){
      const float4 xv = *reinterpret_cast<const float4*>(&s_x[i][r0]);
      const float4 wv = *reinterpret_cast<const float4*>(&s_w[i*HID + u0]);
      float xd[4] = {xv.x, xv.y, xv.z, xv.w};
      float wd[4] = {wv.x, wv.y, wv.z, wv.w};
      #pragma unroll
      for (int r=0;r<4;r++)
        #pragma unroll
        for (int j=0;j<4;j++)
          acc[r][j] = fmaf(xd[r], wd[j], acc[r][j]);
    }
    #pragma unroll
    for (int j=0;j<4;j++){
      const float2 w2 = *reinterpret_cast<const float2*>(&Wm2[(u0+j)*2]);
      #pragma unroll
      for (int r=0;r<4;r++){
        float h = fmaxf(acc[r][j], 0.0f);
        pm[r][0] = fmaf(h, w2.x, pm[r][0]);
        pm[r][1] = fmaf(h, w2.y, pm[r][1]);
      }
    }
  }
  // tree-reduce partials over the 32 lanes sharing rows r0..r0+3
  #pragma unroll
  for (int o=1;o<=16;o<<=1){
    #pragma unroll
    for (int r=0;r<4;r++){
      pd[r][0]+=__shfl_xor(pd[r][0],o,64); pd[r][1]+=__shfl_xor(pd[r][1],o,64);
      pm[r][0]+=__shfl_xor(pm[r][0],o,64); pm[r][1]+=__shfl_xor(pm[r][1],o,64);
    }
  }
  if ((tid & 31) == 0){
    #pragma unroll
    for (int r=0;r<4;r++){
      s_o[r0+r][0] = pd[r][0] + bd2[0];
      s_o[r0+r][1] = pd[r][1] + bd2[1];
      s_o[r0+r][2] = pm[r][0] + bm2[0];
      s_o[r0+r][3] = pm[r][1] + bm2[1];
    }
  }
  __syncthreads();

  if (tid < BR){
    double x = (double)uu[base + tid];
    out[base + tid] = (float)(nlogp_d(x, (double)s_o[tid][0], (double)s_o[tid][1]) +
                              nlogp_d(x, (double)s_o[tid][2], (double)s_o[tid][3]));
  }
}

extern "C" void kernel_launch(void* const* d_in, const int* in_sizes, int n_in,
                              void* d_out, int out_size, void* d_ws, size_t ws_size,
                              hipStream_t stream) {
  const float* encoded = (const float*)d_in[0];
  const float* u       = (const float*)d_in[1];
  const float* Wq1 = (const float*)d_in[2];  const float* bq1 = (const float*)d_in[3];
  const float* Wq2 = (const float*)d_in[4];  const float* bq2 = (const float*)d_in[5];
  const float* Wk1 = (const float*)d_in[6];  const float* bk1 = (const float*)d_in[7];
  const float* Wk2 = (const float*)d_in[8];  const float* bk2 = (const float*)d_in[9];
  const float* Wv1 = (const float*)d_in[10]; const float* bv1 = (const float*)d_in[11];
  const float* Wv2 = (const float*)d_in[12]; const float* bv2 = (const float*)d_in[13];
  const float* role_emb = (const float*)d_in[14];
  const float* Wd1 = (const float*)d_in[15]; const float* bd1 = (const float*)d_in[16];
  const float* Wd2 = (const float*)d_in[17]; const float* bd2 = (const float*)d_in[18];
  const float* Wm1 = (const float*)d_in[19]; const float* bm1 = (const float*)d_in[20];
  const float* Wm2 = (const float*)d_in[21]; const float* bm2 = (const float*)d_in[22];
  const int*   prev_values    = (const int*)d_in[23];
  const int*   next_values    = (const int*)d_in[24];
  const int*   window_indices = (const int*)d_in[25];
  const int*   indices        = (const int*)d_in[26];
  const float* prev_mask   = (const float*)d_in[27];
  const float* next_mask   = (const float*)d_in[28];
  const float* window_mask = (const float*)d_in[29];
  const float* max_depth   = (const float*)d_in[30];
  float* out = (float*)d_out;

  double* mdT = (double*)d_ws;                  // 32768 f64
  float* q  = (float*)(mdT + NROWS);
  float* k  = q  + (size_t)NROWS*DKD;
  float* v  = k  + (size_t)NROWS*DKD;
  float* cx = v  + (size_t)NROWS*DKD;
  int*   pvT  = (int*)(cx + (size_t)NROWS*DKD);
  int*   nvT  = pvT + NROWS;
  int*   idxT = nvT + NROWS;
  float* pmT  = (float*)(idxT + NROWS);
  float* nmT  = pmT + NROWS;

  prep_kernel<<<NROWS/256, 256, 0, stream>>>(max_depth,
      prev_values, next_values, indices, prev_mask, next_mask,
      mdT, pvT, nvT, idxT, pmT, nmT);
  qkv_kernel<<<NROWS/BR, 256, 0, stream>>>(encoded,
      Wq1,bq1,Wq2,bq2, Wk1,bk1,Wk2,bk2, Wv1,bv1,Wv2,bv2, q, k, v);
  attn_kernel<<<NROWS/4, 256, 0, stream>>>(q, k, v, role_emb, mdT,
      pvT, nvT, idxT, pmT, nmT, window_indices, window_mask, cx);
  heads_kernel<<<NROWS/BR, 256, 0, stream>>>(encoded, cx, u,
      Wd1,bd1,Wd2,bd2, Wm1,bm1,Wm2,bm2, out);
}